// Round 11
// baseline (467.051 us; speedup 1.0000x reference)
//
// AttLayer block-local attention, MI355X gfx950.
// R11: break the 8-wave lockstep. All prior variants (R5-R10, 37-38% util)
//   barrier every quadrant phase; with LDS=128KB -> 1 block/CU there are no
//   sibling blocks, so read-phase and MFMA-phase strictly alternate (wall =
//   LDS + MFMA = measured 5810cyc/K-tile). Buffer rotation only needs ONE
//   barrier per K-tile: waves now free-run the 4 quadrants with counted
//   lgkm (per-wave), desyncing so one wave's ds_reads drain under the
//   sibling wave's MFMA. Per tile: [g1(12) g2(4) | LGKM4 Q00 | LGKM0 Q01 |
//   fa47(8) | LGKM0 Q10 Q11 | VM(0) SBAR | stage kt+2 (8 gloads)].
//   Hazards: RAW buf[nxt] staged end kt-1, certified VM(0)+SBAR end kt
//   (1-tile lead ~2500cyc >> 900 HBM); WAR stage-after-barrier with all
//   reads lgkm-certified; reg WAR fa47 issued only after Q01 (fa03 dead).
// Registers identical to R6 (fa[4][2]/fb[4][2]) - no spill risk.
// Workspace: xT | Wqk | Wv | Wo | qkT | v | S | P | guard (attT aliases xT).

#include <hip/hip_runtime.h>
#include <hip/hip_bf16.h>

typedef __attribute__((ext_vector_type(4))) float f32x4;
typedef __attribute__((ext_vector_type(8))) __bf16 bf16x8;

struct ushort4_t { unsigned short x, y, z, w; };

#define DEVINL static __device__ __forceinline__

DEVINL unsigned short f2bf(float f) {  // RTNE float->bf16
  union { float f; unsigned u; } x; x.f = f;
  return (unsigned short)((x.u + 0x7FFFu + ((x.u >> 16) & 1u)) >> 16);
}

DEVINL void gload16(const void* g, void* l) {
  __builtin_amdgcn_global_load_lds((const __attribute__((address_space(1))) void*)g,
                                   (__attribute__((address_space(3))) void*)l,
                                   16, 0, 0);
}

#define SBAR()   asm volatile("s_barrier" ::: "memory")
#define LGKM(n)  asm volatile("s_waitcnt lgkmcnt(" #n ")" ::: "memory")
#define VM(n)    asm volatile("s_waitcnt vmcnt(" #n ")" ::: "memory")
#define SCHED0() __builtin_amdgcn_sched_barrier(0)

// ---------------------------------------------------------------- transpose x
__global__ __launch_bounds__(256) void transpose_x_k(const float* __restrict__ x,
                                                     unsigned short* __restrict__ xT) {
  __shared__ float tile[32][33];
  const int bx = blockIdx.x;  // 512
  const int by = blockIdx.y;  // 64
  const int tx = threadIdx.x; // 32
  const int ty = threadIdx.y; // 8
#pragma unroll
  for (int i = 0; i < 4; ++i) {
    int c = by * 32 + ty + i * 8;
    tile[ty + i * 8][tx] = x[(long)c * 16384 + bx * 32 + tx];
  }
  __syncthreads();
  const int t = ty * 32 + tx;
  const int lrow = t >> 3;
  const int cq = (t & 7) << 2;
  ushort4_t o;
  o.x = f2bf(tile[cq + 0][lrow]);
  o.y = f2bf(tile[cq + 1][lrow]);
  o.z = f2bf(tile[cq + 2][lrow]);
  o.w = f2bf(tile[cq + 3][lrow]);
  *reinterpret_cast<ushort4_t*>(xT + (long)(bx * 32 + lrow) * 2048 + by * 32 + cq) = o;
}

// ------------------------------------------------------------ weight convert
__global__ __launch_bounds__(256) void conv_w_k(const float* __restrict__ wq,
                                                const float* __restrict__ wk,
                                                const float* __restrict__ wv,
                                                const float* __restrict__ wo,
                                                unsigned short* __restrict__ Wqk,
                                                unsigned short* __restrict__ Wv,
                                                unsigned short* __restrict__ Wo) {
  long i = ((long)blockIdx.x * 256 + threadIdx.x) * 4;   // 0..8388604
  const float* src;
  unsigned short* dst;
  if (i < 4194304) {
    src = (i < 2097152) ? (wq + i) : (wk + i - 2097152);
    dst = Wqk + i;
  } else if (i < 6291456) {
    src = wv + (i - 4194304);
    dst = Wv + (i - 4194304);
  } else {
    src = wo + (i - 6291456);
    dst = Wo + (i - 6291456);
  }
  float4 v = *reinterpret_cast<const float4*>(src);
  ushort4_t o{f2bf(v.x), f2bf(v.y), f2bf(v.z), f2bf(v.w)};
  *reinterpret_cast<ushort4_t*>(dst) = o;
}

// ------------------------------------------------------------------ GEMM core
enum { EPI_QK = 0, EPI_V = 1, EPI_S = 2, EPI_PV = 3, EPI_OUT = 4 };

struct GArgs {
  const unsigned short* A;
  const unsigned short* Bt;
  void* C;
  const float* bias;
  const float* bias2;
  const float* mask;
  const unsigned short* guard;
  int aBatch, cBatch;
  int btRow0, btRow0Step, btRowLim;
  int btK0, btK0Step, btKLim;
};

// 256x256 tile, BK=64, 8 waves (2M x 4N), per-wave 128x64.
// LDS: A @ buf*32768, B @ 65536 + buf*32768. ONE barrier per K-tile.
template <int EPI, int GUARDED, int LDA, int LDB, int LDC, int KK>
__global__ __launch_bounds__(512, 2) void gemm8_k(GArgs g) {
  constexpr int NK = KK >> 6;
  __shared__ char lds[131072];

  const int t = threadIdx.x;
  const int l = t & 63;
  const int w = t >> 6;

  // XCD chunk swizzle (all grids % 8 == 0).
  const int gx = gridDim.x, gxy = gx * gridDim.y;
  const int nwg = gxy * gridDim.z;
  int lin = blockIdx.z * gxy + blockIdx.y * gx + blockIdx.x;
  lin = (lin & 7) * (nwg >> 3) + (lin >> 3);
  const int z = lin / gxy;
  const int rres = lin - z * gxy;
  const int Mbase = (rres / gx) << 8;
  const int Nbase = (rres - (rres / gx) * gx) << 8;

  const int wr = w >> 2;
  const int wc = w & 3;
  const int fr = l & 15;
  const int fg = l >> 4;

  const unsigned short* Ab = g.A + (long)z * g.aBatch + (long)Mbase * LDA;
  const int bRowBase = g.btRow0 + z * g.btRow0Step + Nbase;
  const int bK0 = g.btK0 + z * g.btK0Step;

  // ---- staging bases (per-thread, loop-invariant) ----
  const int rr = t >> 3;
  const int cb8s = t & 7;
  const int cbL = cb8s ^ (rr & 7);
  const int bRowT = (rr & 31) + ((rr >> 5) << 6);
  const char* aStageG = (const char*)(Ab + (long)rr * LDA) + (cbL << 4);
  const char* bStageG = (const char*)(g.Bt + (long)(bRowBase + bRowT) * LDB + bK0) + (cbL << 4);
  char* aStageL = lds + rr * 128 + (cb8s << 4);
  char* bStageL = lds + 65536 + bRowT * 128 + (cb8s << 4);

  // stage one 16 KiB unit (2 gloads/thread) of K-tile kt into buf.
  auto stage = [&](int bufSel, int unit, int kt) {
    const int k0b = (kt & (NK - 1)) << 7;
    const bool isA = (unit == 0) || (unit == 3);
#pragma unroll
    for (int gph = 0; gph < 2; ++gph) {
      const int rowAdd = (isA ? (unit == 0 ? 0 : 64) : (unit == 1 ? 0 : 32)) + (gph << 7);
      if (isA) {
        gload16(aStageG + (long)rowAdd * (LDA * 2) + k0b,
                aStageL + bufSel * 32768 + rowAdd * 128);
      } else if (!GUARDED) {
        gload16(bStageG + (long)rowAdd * (LDB * 2) + k0b,
                bStageL + bufSel * 32768 + rowAdd * 128);
      } else {
        const int row = rowAdd + bRowT;
        const int gk = ((kt & (NK - 1)) << 6) + (cbL << 3);
        const int grow = bRowBase + row;
        const int gkk = bK0 + gk;
        const char* gp =
            ((unsigned)grow < (unsigned)g.btRowLim && (unsigned)gkk < (unsigned)g.btKLim)
                ? (const char*)(g.Bt + (long)grow * LDB + gkk)
                : (const char*)g.guard + (l << 4);
        gload16(gp, bStageL + bufSel * 32768 + rowAdd * 128);
      }
    }
  };

  // ---- fragment-read bases: read = base + (BUF*32768 + idx*2048) ----
  const int arow = (wr << 7) + fr;
  const int brow = (wc << 6) + fr;
  const int sA = arow & 7, sB = brow & 7;
  const char* aRd0 = lds + arow * 128 + ((fg ^ sA) << 4);
  const char* aRd1 = lds + arow * 128 + (((4 | fg) ^ sA) << 4);
  const char* bRd0 = lds + 65536 + brow * 128 + ((fg ^ sB) << 4);
  const char* bRd1 = lds + 65536 + brow * 128 + (((4 | fg) ^ sB) << 4);

  f32x4 acc[8][4];
#pragma unroll
  for (int i = 0; i < 8; ++i)
#pragma unroll
    for (int j = 0; j < 4; ++j) acc[i][j] = f32x4{0.f, 0.f, 0.f, 0.f};

  bf16x8 fa[4][2], fb[4][2];

#define RA(slot, i8, B) \
  { fa[slot][0] = *(const bf16x8*)(aRd0 + ((B)*32768 + (i8)*2048)); \
    fa[slot][1] = *(const bf16x8*)(aRd1 + ((B)*32768 + (i8)*2048)); }
#define RB(j, B) \
  { fb[j][0] = *(const bf16x8*)(bRd0 + ((B)*32768 + (j)*2048)); \
    fb[j][1] = *(const bf16x8*)(bRd1 + ((B)*32768 + (j)*2048)); }

// kk-outer: dependent MFMAs on the same acc are spaced 8 apart.
#define MFMA_Q(QI, QJ)                                                        \
  __builtin_amdgcn_s_setprio(1);                                              \
  _Pragma("unroll") for (int kk = 0; kk < 2; ++kk)                            \
  _Pragma("unroll") for (int i = 0; i < 4; ++i)                               \
  _Pragma("unroll") for (int j = 0; j < 2; ++j)                               \
    acc[(QI)*4 + i][(QJ)*2 + j] = __builtin_amdgcn_mfma_f32_16x16x32_bf16(    \
        fa[i][kk], fb[(QJ)*2 + j][kk], acc[(QI)*4 + i][(QJ)*2 + j], 0, 0, 0); \
  __builtin_amdgcn_s_setprio(0);

  // prologue: buf0 (kt0) + buf1 (kt1), 16 gloads; certify buf0 only.
  stage(0, 0, 0); stage(0, 1, 0); stage(0, 2, 0); stage(0, 3, 0);
  stage(1, 0, 1); stage(1, 1, 1); stage(1, 2, 1); stage(1, 3, 1);
  VM(8);        // buf0 (oldest 8) landed; buf1's 8 stay in flight
  SBAR();

#pragma unroll 1
  for (int kt = 0; kt < NK; ++kt) {
    const int cur = kt & 1;
    // g1: fa03 + fb01 (12 reads)
    RA(0, 0, cur) RA(1, 1, cur) RA(2, 2, cur) RA(3, 3, cur)
    RB(0, cur) RB(1, cur)
    SCHED0();   // pin g1 before g2 (counted-lgkm correctness)
    // g2: fb23 (4 reads) — drains under Q00
    RB(2, cur) RB(3, cur)
    LGKM(4); SCHED0();            // g1 complete
    MFMA_Q(0, 0);                 // fa03 x fb01
    LGKM(0); SCHED0();            // fb23 complete (mostly drained already)
    MFMA_Q(0, 1);                 // fa03 x fb23  (fa03 last use)
    // g3: fa47 reusing fa slots — drains under Q01's tail
    RA(0, 4, cur) RA(1, 5, cur) RA(2, 6, cur) RA(3, 7, cur)
    LGKM(0); SCHED0();            // fa47 complete
    MFMA_Q(1, 0);                 // fa47 x fb01
    MFMA_Q(1, 1);                 // fa47 x fb23
    // rotate: certify buf[nxt] (staged end of kt-1), then restage buf[cur]
    VM(0);                        // ~free: only 8 one-tile-old gloads in flight
    SBAR();                       // all waves done reading buf[cur]; buf[nxt] ready
    stage(cur, 0, kt + 2); stage(cur, 1, kt + 2);
    stage(cur, 2, kt + 2); stage(cur, 3, kt + 2);
  }
  VM(0); LGKM(0); SBAR();  // drain wrapped prefetches before epilogue

  // epilogue: D row=(lane>>4)*4+r, col=lane&15 within each 16x16 fragment
#pragma unroll
  for (int ii = 0; ii < 8; ++ii)
#pragma unroll
    for (int j = 0; j < 4; ++j)
#pragma unroll
      for (int r = 0; r < 4; ++r) {
        const int row = Mbase + (wr << 7) + ii * 16 + fg * 4 + r;
        const int col = Nbase + (wc << 6) + j * 16 + fr;
        float val = acc[ii][j][r];
        const long off = (long)z * g.cBatch + (long)row * LDC + col;
        if (EPI == EPI_QK) {
          val = (col < 1024) ? (val + g.bias[col]) * 0.03125f
                             : (val + g.bias2[col - 1024]);
          ((unsigned short*)g.C)[off] = f2bf(val);
        } else if (EPI == EPI_V) {
          val += g.bias[row];
          ((unsigned short*)g.C)[off] = f2bf(val);
        } else if (EPI == EPI_S) {
          ((float*)g.C)[off] = val;
        } else if (EPI == EPI_PV) {
          val = fmaxf(val, 0.f);
          ((unsigned short*)g.C)[off] = f2bf(val);
        } else {
          val = (val + g.bias[row]) * g.mask[col];
          ((float*)g.C)[off] = val;
        }
      }
#undef MFMA_Q
#undef RA
#undef RB
}

// ------------------------------------------------------------------- softmax
__global__ __launch_bounds__(256) void softmax_k(const float* __restrict__ S,
                                                 const float* __restrict__ mask,
                                                 unsigned short* __restrict__ P) {
  const int row = blockIdx.x;      // n*512 + l
  const int n = row >> 9;
  const float* s = S + (long)row * 1024;
  unsigned short* p = P + (long)row * 1024;
  const int t = threadIdx.x;

  const float4 sv = *reinterpret_cast<const float4*>(s + t * 4);
  const int pos0 = (n << 9) + t * 4 - 256;
  float4 mv = {0.f, 0.f, 0.f, 0.f};
  if ((unsigned)pos0 < 16384u) mv = *reinterpret_cast<const float4*>(mask + pos0);
  float fm[4] = {mv.x, mv.y, mv.z, mv.w};
  if (t == 255) fm[3] = 0.f;       // m == 1023 excluded by window mask
  const float sc[4] = {sv.x, sv.y, sv.z, sv.w};

  float logit[4];
  float lmax = -3.0e38f;
#pragma unroll
  for (int k = 0; k < 4; ++k) {
    logit[k] = sc[k] + logf(fm[k] + 1e-9f);
    lmax = fmaxf(lmax, logit[k]);
  }
#pragma unroll
  for (int o = 32; o; o >>= 1) lmax = fmaxf(lmax, __shfl_xor(lmax, o, 64));
  __shared__ float red[8];
  const int wv_ = t >> 6, ln = t & 63;
  if (ln == 0) red[wv_] = lmax;
  __syncthreads();
  const float gmax = fmaxf(fmaxf(red[0], red[1]), fmaxf(red[2], red[3]));

  float e[4], lsum = 0.f;
#pragma unroll
  for (int k = 0; k < 4; ++k) { e[k] = expf(logit[k] - gmax); lsum += e[k]; }
#pragma unroll
  for (int o = 32; o; o >>= 1) lsum += __shfl_xor(lsum, o, 64);
  if (ln == 0) red[4 + wv_] = lsum;
  __syncthreads();
  const float inv = 1.f / ((red[4] + red[5]) + (red[6] + red[7]));
  ushort4_t o4;
  o4.x = f2bf(e[0] * inv * fm[0]);
  o4.y = f2bf(e[1] * inv * fm[1]);
  o4.z = f2bf(e[2] * inv * fm[2]);
  o4.w = f2bf(e[3] * inv * fm[3]);
  *reinterpret_cast<ushort4_t*>(p + t * 4) = o4;
}

// -------------------------------------------------------------------- launch
extern "C" void kernel_launch(void* const* d_in, const int* in_sizes, int n_in,
                              void* d_out, int out_size, void* d_ws, size_t ws_size,
                              hipStream_t stream) {
  const float* x1 = (const float*)d_in[0];
  const float* mask = (const float*)d_in[2];
  const float* wq = (const float*)d_in[3];
  const float* bq = (const float*)d_in[4];
  const float* wk = (const float*)d_in[5];
  const float* bk = (const float*)d_in[6];
  const float* wv = (const float*)d_in[7];
  const float* bv = (const float*)d_in[8];
  const float* wo = (const float*)d_in[9];
  const float* bo = (const float*)d_in[10];

  char* ws = (char*)d_ws;
  unsigned short* xT   = (unsigned short*)(ws);
  unsigned short* attT = xT;                                     // alias
  unsigned short* Wqk  = (unsigned short*)(ws + 67108864);
  unsigned short* Wv   = (unsigned short*)(ws + 75497472);
  unsigned short* Wo   = (unsigned short*)(ws + 79691776);
  unsigned short* qkT  = (unsigned short*)(ws + 83886080);
  unsigned short* vbuf = (unsigned short*)(ws + 150994944);
  float*          Sbuf = (float*)(ws + 184549376);
  unsigned short* P    = (unsigned short*)(ws + 251658240);
  unsigned short* guard= (unsigned short*)(ws + 285212672);

  hipMemsetAsync(guard, 0, 4096, stream);

  transpose_x_k<<<dim3(512, 64), dim3(32, 8), 0, stream>>>(x1, xT);
  conv_w_k<<<dim3(8192), dim3(256), 0, stream>>>(wq, wk, wv, wo, Wqk, Wv, Wo);

  const int BIG = 0x40000000;
  // 1) qkT[16384][2048] = xT @ Wqk^T (+bias, q-part scaled 1/32)
  {
    GArgs a{};
    a.A = xT; a.Bt = Wqk; a.C = qkT;
    a.bias = bq; a.bias2 = bk; a.guard = guard;
    a.aBatch = 0; a.cBatch = 0;
    a.btRow0 = 0; a.btRow0Step = 0; a.btRowLim = BIG;
    a.btK0 = 0; a.btK0Step = 0; a.btKLim = BIG;
    gemm8_k<EPI_QK, 0, 2048, 2048, 2048, 2048><<<dim3(8, 64, 1), 512, 0, stream>>>(a);
  }
  // 2) v[1024][16384] = Wv @ x (+bv)
  {
    GArgs a{};
    a.A = Wv; a.Bt = xT; a.C = vbuf;
    a.bias = bv; a.guard = guard;
    a.aBatch = 0; a.cBatch = 0;
    a.btRow0 = 0; a.btRow0Step = 0; a.btRowLim = BIG;
    a.btK0 = 0; a.btK0Step = 0; a.btKLim = BIG;
    gemm8_k<EPI_V, 0, 2048, 2048, 16384, 2048><<<dim3(64, 4, 1), 512, 0, stream>>>(a);
  }
  // 3) S[n][512][1024] = Qb @ Kb^T (halo rows via guard)
  {
    GArgs a{};
    a.A = qkT; a.Bt = qkT; a.C = Sbuf;
    a.guard = guard;
    a.aBatch = 512 * 2048; a.cBatch = 512 * 1024;
    a.btRow0 = -256; a.btRow0Step = 512; a.btRowLim = 16384;
    a.btK0 = 1024; a.btK0Step = 0; a.btKLim = BIG;
    gemm8_k<EPI_S, 1, 2048, 2048, 1024, 1024><<<dim3(4, 2, 32), 512, 0, stream>>>(a);
  }
  // 4) softmax rows -> P bf16
  softmax_k<<<dim3(16384), dim3(256), 0, stream>>>(Sbuf, mask, P);
  // 5) attT[n][512][1024] = relu(P @ Vb^T) (halo cols via guard)
  {
    GArgs a{};
    a.A = P; a.Bt = vbuf; a.C = attT;
    a.guard = guard;
    a.aBatch = 512 * 1024; a.cBatch = 512 * 1024;
    a.btRow0 = 0; a.btRow0Step = 0; a.btRowLim = BIG;
    a.btK0 = -256; a.btK0Step = 512; a.btKLim = 16384;
    gemm8_k<EPI_PV, 1, 1024, 16384, 1024, 1024><<<dim3(4, 2, 32), 512, 0, stream>>>(a);
  }
  // 6) out[2048][16384] = (Wo @ attT^T + bo) * mask (fp32)
  {
    GArgs a{};
    a.A = Wo; a.Bt = attT; a.C = d_out;
    a.bias = bo; a.mask = mask; a.guard = guard;
    a.aBatch = 0; a.cBatch = 0;
    a.btRow0 = 0; a.btRow0Step = 0; a.btRowLim = BIG;
    a.btK0 = 0; a.btK0Step = 0; a.btKLim = BIG;
    gemm8_k<EPI_OUT, 0, 1024, 1024, 16384, 1024><<<dim3(64, 8, 1), 512, 0, stream>>>(a);
  }
  (void)in_sizes; (void)n_in; (void)out_size; (void)ws_size;
}

// Round 12
// 458.554 us; speedup vs baseline: 1.0185x; 1.0185x over previous
//
// AttLayer block-local attention, MI355X gfx950.
// R12: remove the self-defeating "memory" clobbers. All R2-R11 waitcnt/barrier
//   macros were asm volatile(...:::"memory"); the AMDGPU waitcnt pass inserts
//   a conservative vmcnt(0)+lgkmcnt(0) drain before any may-touch-memory asm
//   (global_load_lds writes LDS, tracked by vmcnt) -> every phase boundary
//   secretly drained -> counted VM(6) was dead code -> all five schedule
//   variants measured identically at the drain0 level (890TF = guide's m218-V1
//   / 2-phase band). Fix = m201's exact forms: __builtin_amdgcn_s_barrier(),
//   clobber-free asm waitcnts, sched_barrier(0) fences pinning program order
//   (reads->fence->count; wait->fence->MFMA; barrier->fence->reads) so counted
//   waits stay correct without compiler drains. Schedule/counts = R10 (audited).
// Workspace: xT | Wqk | Wv | Wo | qkT | v | S | P | guard (attT aliases xT).

#include <hip/hip_runtime.h>
#include <hip/hip_bf16.h>

typedef __attribute__((ext_vector_type(4))) float f32x4;
typedef __attribute__((ext_vector_type(8))) __bf16 bf16x8;

struct ushort4_t { unsigned short x, y, z, w; };

#define DEVINL static __device__ __forceinline__

DEVINL unsigned short f2bf(float f) {  // RTNE float->bf16
  union { float f; unsigned u; } x; x.f = f;
  return (unsigned short)((x.u + 0x7FFFu + ((x.u >> 16) & 1u)) >> 16);
}

DEVINL void gload16(const void* g, void* l) {
  __builtin_amdgcn_global_load_lds((const __attribute__((address_space(1))) void*)g,
                                   (__attribute__((address_space(3))) void*)l,
                                   16, 0, 0);
}

// Clobber-free: no compiler-inserted conservative drains (R12 hypothesis).
#define SBAR()   __builtin_amdgcn_s_barrier()
#define LGKM(n)  asm volatile("s_waitcnt lgkmcnt(" #n ")")
#define VM(n)    asm volatile("s_waitcnt vmcnt(" #n ")")
#define SCHED0() __builtin_amdgcn_sched_barrier(0)

// ---------------------------------------------------------------- transpose x
__global__ __launch_bounds__(256) void transpose_x_k(const float* __restrict__ x,
                                                     unsigned short* __restrict__ xT) {
  __shared__ float tile[32][33];
  const int bx = blockIdx.x;  // 512
  const int by = blockIdx.y;  // 64
  const int tx = threadIdx.x; // 32
  const int ty = threadIdx.y; // 8
#pragma unroll
  for (int i = 0; i < 4; ++i) {
    int c = by * 32 + ty + i * 8;
    tile[ty + i * 8][tx] = x[(long)c * 16384 + bx * 32 + tx];
  }
  __syncthreads();
  const int t = ty * 32 + tx;
  const int lrow = t >> 3;
  const int cq = (t & 7) << 2;
  ushort4_t o;
  o.x = f2bf(tile[cq + 0][lrow]);
  o.y = f2bf(tile[cq + 1][lrow]);
  o.z = f2bf(tile[cq + 2][lrow]);
  o.w = f2bf(tile[cq + 3][lrow]);
  *reinterpret_cast<ushort4_t*>(xT + (long)(bx * 32 + lrow) * 2048 + by * 32 + cq) = o;
}

// ------------------------------------------------------------ weight convert
__global__ __launch_bounds__(256) void conv_w_k(const float* __restrict__ wq,
                                                const float* __restrict__ wk,
                                                const float* __restrict__ wv,
                                                const float* __restrict__ wo,
                                                unsigned short* __restrict__ Wqk,
                                                unsigned short* __restrict__ Wv,
                                                unsigned short* __restrict__ Wo) {
  long i = ((long)blockIdx.x * 256 + threadIdx.x) * 4;   // 0..8388604
  const float* src;
  unsigned short* dst;
  if (i < 4194304) {
    src = (i < 2097152) ? (wq + i) : (wk + i - 2097152);
    dst = Wqk + i;
  } else if (i < 6291456) {
    src = wv + (i - 4194304);
    dst = Wv + (i - 4194304);
  } else {
    src = wo + (i - 6291456);
    dst = Wo + (i - 6291456);
  }
  float4 v = *reinterpret_cast<const float4*>(src);
  ushort4_t o{f2bf(v.x), f2bf(v.y), f2bf(v.z), f2bf(v.w)};
  *reinterpret_cast<ushort4_t*>(dst) = o;
}

// ------------------------------------------------------------------ GEMM core
enum { EPI_QK = 0, EPI_V = 1, EPI_S = 2, EPI_PV = 3, EPI_OUT = 4 };

struct GArgs {
  const unsigned short* A;
  const unsigned short* Bt;
  void* C;
  const float* bias;
  const float* bias2;
  const float* mask;
  const unsigned short* guard;
  int aBatch, cBatch;
  int btRow0, btRow0Step, btRowLim;
  int btK0, btK0Step, btKLim;
};

// 256x256 tile, BK=64, 8 waves (2M x 4N), per-wave 128x64, 8-phase pipeline.
// LDS: A @ buf*32768, B @ 65536 + buf*32768.
template <int EPI, int GUARDED, int LDA, int LDB, int LDC, int KK>
__global__ __launch_bounds__(512, 2) void gemm8_k(GArgs g) {
  constexpr int NK = KK >> 6;
  constexpr int NT = NK >> 1;
  __shared__ char lds[131072];

  const int t = threadIdx.x;
  const int l = t & 63;
  const int w = t >> 6;

  // XCD chunk swizzle (all grids % 8 == 0).
  const int gx = gridDim.x, gxy = gx * gridDim.y;
  const int nwg = gxy * gridDim.z;
  int lin = blockIdx.z * gxy + blockIdx.y * gx + blockIdx.x;
  lin = (lin & 7) * (nwg >> 3) + (lin >> 3);
  const int z = lin / gxy;
  const int rres = lin - z * gxy;
  const int Mbase = (rres / gx) << 8;
  const int Nbase = (rres - (rres / gx) * gx) << 8;

  const int wr = w >> 2;
  const int wc = w & 3;
  const int fr = l & 15;
  const int fg = l >> 4;

  const unsigned short* Ab = g.A + (long)z * g.aBatch + (long)Mbase * LDA;
  const int bRowBase = g.btRow0 + z * g.btRow0Step + Nbase;
  const int bK0 = g.btK0 + z * g.btK0Step;

  // ---- staging bases (per-thread, loop-invariant) ----
  const int rr = t >> 3;
  const int cb8s = t & 7;
  const int cbL = cb8s ^ (rr & 7);
  const int bRowT = (rr & 31) + ((rr >> 5) << 6);
  const char* aStageG = (const char*)(Ab + (long)rr * LDA) + (cbL << 4);
  const char* bStageG = (const char*)(g.Bt + (long)(bRowBase + bRowT) * LDB + bK0) + (cbL << 4);
  char* aStageL = lds + rr * 128 + (cb8s << 4);
  char* bStageL = lds + 65536 + bRowT * 128 + (cb8s << 4);

  // stage one 16 KiB unit (2 gloads/thread) of K-tile kt into buf.
  auto stage = [&](int bufSel, int unit, int kt) {
    const int k0b = (kt & (NK - 1)) << 7;
    const bool isA = (unit == 0) || (unit == 3);
#pragma unroll
    for (int gph = 0; gph < 2; ++gph) {
      const int rowAdd = (isA ? (unit == 0 ? 0 : 64) : (unit == 1 ? 0 : 32)) + (gph << 7);
      if (isA) {
        gload16(aStageG + (long)rowAdd * (LDA * 2) + k0b,
                aStageL + bufSel * 32768 + rowAdd * 128);
      } else if (!GUARDED) {
        gload16(bStageG + (long)rowAdd * (LDB * 2) + k0b,
                bStageL + bufSel * 32768 + rowAdd * 128);
      } else {
        const int row = rowAdd + bRowT;
        const int gk = ((kt & (NK - 1)) << 6) + (cbL << 3);
        const int grow = bRowBase + row;
        const int gkk = bK0 + gk;
        const char* gp =
            ((unsigned)grow < (unsigned)g.btRowLim && (unsigned)gkk < (unsigned)g.btKLim)
                ? (const char*)(g.Bt + (long)grow * LDB + gkk)
                : (const char*)g.guard + (l << 4);
        gload16(gp, bStageL + bufSel * 32768 + rowAdd * 128);
      }
    }
  };

  // ---- fragment-read bases: read = base + (BUF*32768 + idx*2048) ----
  const int arow = (wr << 7) + fr;
  const int brow = (wc << 6) + fr;
  const int sA = arow & 7, sB = brow & 7;
  const char* aRd0 = lds + arow * 128 + ((fg ^ sA) << 4);
  const char* aRd1 = lds + arow * 128 + (((4 | fg) ^ sA) << 4);
  const char* bRd0 = lds + 65536 + brow * 128 + ((fg ^ sB) << 4);
  const char* bRd1 = lds + 65536 + brow * 128 + (((4 | fg) ^ sB) << 4);

  f32x4 acc[8][4];
#pragma unroll
  for (int i = 0; i < 8; ++i)
#pragma unroll
    for (int j = 0; j < 4; ++j) acc[i][j] = f32x4{0.f, 0.f, 0.f, 0.f};

  bf16x8 fa[4][2], fb[4][2];

#define RA(slot, i8, B) \
  { fa[slot][0] = *(const bf16x8*)(aRd0 + ((B)*32768 + (i8)*2048)); \
    fa[slot][1] = *(const bf16x8*)(aRd1 + ((B)*32768 + (i8)*2048)); }
#define RB(j, B) \
  { fb[j][0] = *(const bf16x8*)(bRd0 + ((B)*32768 + (j)*2048)); \
    fb[j][1] = *(const bf16x8*)(bRd1 + ((B)*32768 + (j)*2048)); }

// kk-outer: dependent MFMAs on the same acc are spaced 8 apart.
#define MFMA_Q(QI, QJ)                                                        \
  __builtin_amdgcn_s_setprio(1);                                              \
  _Pragma("unroll") for (int kk = 0; kk < 2; ++kk)                            \
  _Pragma("unroll") for (int i = 0; i < 4; ++i)                               \
  _Pragma("unroll") for (int j = 0; j < 2; ++j)                               \
    acc[(QI)*4 + i][(QJ)*2 + j] = __builtin_amdgcn_mfma_f32_16x16x32_bf16(    \
        fa[i][kk], fb[(QJ)*2 + j][kk], acc[(QI)*4 + i][(QJ)*2 + j], 0, 0, 0); \
  __builtin_amdgcn_s_setprio(0);

  // prologue: buf0 fully (kt0), buf1 units 0-2 (kt1). 14 gloads in flight.
  stage(0, 0, 0); stage(0, 1, 0); stage(0, 2, 0); stage(0, 3, 0);
  stage(1, 0, 1); stage(1, 1, 1); stage(1, 2, 1);
  VM(6);        // oldest 8 (all of buf0) landed; buf1's 6 stay in flight
  SBAR();

#pragma unroll 1
  for (int it = 0; it < NT; ++it) {
    const int kt1 = 2 * it + 1;
    const int ktn0 = 2 * it + 2;
    const int ktn1 = 2 * it + 3;
    // ---- phase 0 (buf0, Q00): 12 reads + lgkm(8) pacing
    SCHED0();                       // reads may not hoist above prior SBAR
    RA(0, 0, 0) RA(1, 1, 0) RA(2, 2, 0) RA(3, 3, 0)
    RB(0, 0) RB(1, 0)
    SCHED0();                       // pin reads before the counted wait
    stage(1, 3, kt1);
    LGKM(8); SCHED0();
    SBAR();
    LGKM(0); SCHED0();              // rule #18: fence between wait and MFMA
    MFMA_Q(0, 0);
    SBAR();
    // ---- phase 1 (buf0, Q01)
    SCHED0();
    RB(2, 0) RB(3, 0)
    SCHED0();
    stage(0, 0, ktn0);
    SBAR();
    LGKM(0); SCHED0();
    MFMA_Q(0, 1);
    SBAR();
    // ---- phase 2 (buf0, Q10)
    SCHED0();
    RA(0, 4, 0) RA(1, 5, 0) RA(2, 6, 0) RA(3, 7, 0)
    SCHED0();
    stage(0, 1, ktn0);
    SBAR();
    LGKM(0); SCHED0();
    MFMA_Q(1, 0);
    SBAR();
    // ---- phase 3 (buf0, Q11)
    stage(0, 2, ktn0);
    SBAR();
    LGKM(0); SCHED0();
    MFMA_Q(1, 1);
    VM(6); SCHED0();                // buf1 (kt1) fully landed before phase 4
    SBAR();
    // ---- phase 4 (buf1, Q00): 12 reads + lgkm(8) pacing
    SCHED0();
    RA(0, 0, 1) RA(1, 1, 1) RA(2, 2, 1) RA(3, 3, 1)
    RB(0, 1) RB(1, 1)
    SCHED0();
    stage(0, 3, ktn0);
    LGKM(8); SCHED0();
    SBAR();
    LGKM(0); SCHED0();
    MFMA_Q(0, 0);
    SBAR();
    // ---- phase 5 (buf1, Q01)
    SCHED0();
    RB(2, 1) RB(3, 1)
    SCHED0();
    stage(1, 0, ktn1);
    SBAR();
    LGKM(0); SCHED0();
    MFMA_Q(0, 1);
    SBAR();
    // ---- phase 6 (buf1, Q10)
    SCHED0();
    RA(0, 4, 1) RA(1, 5, 1) RA(2, 6, 1) RA(3, 7, 1)
    SCHED0();
    stage(1, 1, ktn1);
    SBAR();
    LGKM(0); SCHED0();
    MFMA_Q(1, 0);
    SBAR();
    // ---- phase 7 (buf1, Q11)
    stage(1, 2, ktn1);
    SBAR();
    LGKM(0); SCHED0();
    MFMA_Q(1, 1);
    VM(6); SCHED0();                // buf0 (ktn0) fully landed before next P0
    SBAR();
  }
  VM(0); LGKM(0); SCHED0(); SBAR();  // final drain before epilogue

  // epilogue: D row=(lane>>4)*4+r, col=lane&15 within each 16x16 fragment
#pragma unroll
  for (int ii = 0; ii < 8; ++ii)
#pragma unroll
    for (int j = 0; j < 4; ++j)
#pragma unroll
      for (int r = 0; r < 4; ++r) {
        const int row = Mbase + (wr << 7) + ii * 16 + fg * 4 + r;
        const int col = Nbase + (wc << 6) + j * 16 + fr;
        float val = acc[ii][j][r];
        const long off = (long)z * g.cBatch + (long)row * LDC + col;
        if (EPI == EPI_QK) {
          val = (col < 1024) ? (val + g.bias[col]) * 0.03125f
                             : (val + g.bias2[col - 1024]);
          ((unsigned short*)g.C)[off] = f2bf(val);
        } else if (EPI == EPI_V) {
          val += g.bias[row];
          ((unsigned short*)g.C)[off] = f2bf(val);
        } else if (EPI == EPI_S) {
          ((float*)g.C)[off] = val;
        } else if (EPI == EPI_PV) {
          val = fmaxf(val, 0.f);
          ((unsigned short*)g.C)[off] = f2bf(val);
        } else {
          val = (val + g.bias[row]) * g.mask[col];
          ((float*)g.C)[off] = val;
        }
      }
#undef MFMA_Q
#undef RA
#undef RB
}

// ------------------------------------------------------------------- softmax
__global__ __launch_bounds__(256) void softmax_k(const float* __restrict__ S,
                                                 const float* __restrict__ mask,
                                                 unsigned short* __restrict__ P) {
  const int row = blockIdx.x;      // n*512 + l
  const int n = row >> 9;
  const float* s = S + (long)row * 1024;
  unsigned short* p = P + (long)row * 1024;
  const int t = threadIdx.x;

  const float4 sv = *reinterpret_cast<const float4*>(s + t * 4);
  const int pos0 = (n << 9) + t * 4 - 256;
  float4 mv = {0.f, 0.f, 0.f, 0.f};
  if ((unsigned)pos0 < 16384u) mv = *reinterpret_cast<const float4*>(mask + pos0);
  float fm[4] = {mv.x, mv.y, mv.z, mv.w};
  if (t == 255) fm[3] = 0.f;       // m == 1023 excluded by window mask
  const float sc[4] = {sv.x, sv.y, sv.z, sv.w};

  float logit[4];
  float lmax = -3.0e38f;
#pragma unroll
  for (int k = 0; k < 4; ++k) {
    logit[k] = sc[k] + logf(fm[k] + 1e-9f);
    lmax = fmaxf(lmax, logit[k]);
  }
#pragma unroll
  for (int o = 32; o; o >>= 1) lmax = fmaxf(lmax, __shfl_xor(lmax, o, 64));
  __shared__ float red[8];
  const int wv_ = t >> 6, ln = t & 63;
  if (ln == 0) red[wv_] = lmax;
  __syncthreads();
  const float gmax = fmaxf(fmaxf(red[0], red[1]), fmaxf(red[2], red[3]));

  float e[4], lsum = 0.f;
#pragma unroll
  for (int k = 0; k < 4; ++k) { e[k] = expf(logit[k] - gmax); lsum += e[k]; }
#pragma unroll
  for (int o = 32; o; o >>= 1) lsum += __shfl_xor(lsum, o, 64);
  if (ln == 0) red[4 + wv_] = lsum;
  __syncthreads();
  const float inv = 1.f / ((red[4] + red[5]) + (red[6] + red[7]));
  ushort4_t o4;
  o4.x = f2bf(e[0] * inv * fm[0]);
  o4.y = f2bf(e[1] * inv * fm[1]);
  o4.z = f2bf(e[2] * inv * fm[2]);
  o4.w = f2bf(e[3] * inv * fm[3]);
  *reinterpret_cast<ushort4_t*>(p + t * 4) = o4;
}

// -------------------------------------------------------------------- launch
extern "C" void kernel_launch(void* const* d_in, const int* in_sizes, int n_in,
                              void* d_out, int out_size, void* d_ws, size_t ws_size,
                              hipStream_t stream) {
  const float* x1 = (const float*)d_in[0];
  const float* mask = (const float*)d_in[2];
  const float* wq = (const float*)d_in[3];
  const float* bq = (const float*)d_in[4];
  const float* wk = (const float*)d_in[5];
  const float* bk = (const float*)d_in[6];
  const float* wv = (const float*)d_in[7];
  const float* bv = (const float*)d_in[8];
  const float* wo = (const float*)d_in[9];
  const float* bo = (const float*)d_in[10];

  char* ws = (char*)d_ws;
  unsigned short* xT   = (unsigned short*)(ws);
  unsigned short* attT = xT;                                     // alias
  unsigned short* Wqk  = (unsigned short*)(ws + 67108864);
  unsigned short* Wv   = (unsigned short*)(ws + 75497472);
  unsigned short* Wo   = (unsigned short*)(ws + 79691776);
  unsigned short* qkT  = (unsigned short*)(ws + 83886080);
  unsigned short* vbuf = (unsigned short*)(ws + 150994944);
  float*          Sbuf = (float*)(ws + 184549376);
  unsigned short* P    = (unsigned short*)(ws + 251658240);
  unsigned short* guard= (unsigned short*)(ws + 285212672);

  hipMemsetAsync(guard, 0, 4096, stream);

  transpose_x_k<<<dim3(512, 64), dim3(32, 8), 0, stream>>>(x1, xT);
  conv_w_k<<<dim3(8192), dim3(256), 0, stream>>>(wq, wk, wv, wo, Wqk, Wv, Wo);

  const int BIG = 0x40000000;
  // 1) qkT[16384][2048] = xT @ Wqk^T (+bias, q-part scaled 1/32)
  {
    GArgs a{};
    a.A = xT; a.Bt = Wqk; a.C = qkT;
    a.bias = bq; a.bias2 = bk; a.guard = guard;
    a.aBatch = 0; a.cBatch = 0;
    a.btRow0 = 0; a.btRow0Step = 0; a.btRowLim = BIG;
    a.btK0 = 0; a.btK0Step = 0; a.btKLim = BIG;
    gemm8_k<EPI_QK, 0, 2048, 2048, 2048, 2048><<<dim3(8, 64, 1), 512, 0, stream>>>(a);
  }
  // 2) v[1024][16384] = Wv @ x (+bv)
  {
    GArgs a{};
    a.A = Wv; a.Bt = xT; a.C = vbuf;
    a.bias = bv; a.guard = guard;
    a.aBatch = 0; a.cBatch = 0;
    a.btRow0 = 0; a.btRow0Step = 0; a.btRowLim = BIG;
    a.btK0 = 0; a.btK0Step = 0; a.btKLim = BIG;
    gemm8_k<EPI_V, 0, 2048, 2048, 16384, 2048><<<dim3(64, 4, 1), 512, 0, stream>>>(a);
  }
  // 3) S[n][512][1024] = Qb @ Kb^T (halo rows via guard)
  {
    GArgs a{};
    a.A = qkT; a.Bt = qkT; a.C = Sbuf;
    a.guard = guard;
    a.aBatch = 512 * 2048; a.cBatch = 512 * 1024;
    a.btRow0 = -256; a.btRow0Step = 512; a.btRowLim = 16384;
    a.btK0 = 1024; a.btK0Step = 0; a.btKLim = BIG;
    gemm8_k<EPI_S, 1, 2048, 2048, 1024, 1024><<<dim3(4, 2, 32), 512, 0, stream>>>(a);
  }
  // 4) softmax rows -> P bf16
  softmax_k<<<dim3(16384), dim3(256), 0, stream>>>(Sbuf, mask, P);
  // 5) attT[n][512][1024] = relu(P @ Vb^T) (halo cols via guard)
  {
    GArgs a{};
    a.A = P; a.Bt = vbuf; a.C = attT;
    a.guard = guard;
    a.aBatch = 512 * 1024; a.cBatch = 512 * 1024;
    a.btRow0 = 0; a.btRow0Step = 0; a.btRowLim = BIG;
    a.btK0 = -256; a.btK0Step = 512; a.btKLim = 16384;
    gemm8_k<EPI_PV, 1, 1024, 16384, 1024, 1024><<<dim3(4, 2, 32), 512, 0, stream>>>(a);
  }
  // 6) out[2048][16384] = (Wo @ attT^T + bo) * mask (fp32)
  {
    GArgs a{};
    a.A = Wo; a.Bt = attT; a.C = d_out;
    a.bias = bo; a.mask = mask; a.guard = guard;
    a.aBatch = 0; a.cBatch = 0;
    a.btRow0 = 0; a.btRow0Step = 0; a.btRowLim = BIG;
    a.btK0 = 0; a.btK0Step = 0; a.btKLim = BIG;
    gemm8_k<EPI_OUT, 0, 1024, 1024, 16384, 1024><<<dim3(64, 8, 1), 512, 0, stream>>>(a);
  }
  (void)in_sizes; (void)n_in; (void)out_size; (void)ws_size;
}